// Round 4
// baseline (313.989 us; speedup 1.0000x reference)
//
#include <hip/hip_runtime.h>
#include <hip/hip_cooperative_groups.h>
#include <hip/hip_bf16.h>

namespace cg = cooperative_groups;

// CrossNetLayer: h = x @ W_enc + b_enc; then 4 cross layers
//   s = x_l . w_l (per row); x_l += x0 * s + b_l
// B = D = H = 1024, DEPTH = 4. fp32 in/out; GEMM internally f16 MFMA.
//
// R4: ONE cooperative kernel, 512 blocks x 256 thr (2 blocks/CU).
// Phase 1: W transpose-cast + x cast. Phase 2: tiled GEMM (BM=32 BN=64
// BK=64, dbuf swizzled LDS, global_load_lds). Phase 3: crossnet, 2 rows
// per block. grid.sync() between phases. Kills 2 dispatch boundaries and
// per-kernel ramp; avoids R3's reuse mistake (192 KB L2 pull per block,
// not 2 MB).

#define B_SZ 1024
#define D_SZ 1024
#define H_SZ 1024
#define DEPTH 4

typedef _Float16 half4_t __attribute__((ext_vector_type(4)));
typedef _Float16 half8_t __attribute__((ext_vector_type(8)));
typedef float floatx4_t __attribute__((ext_vector_type(4)));

typedef const __attribute__((address_space(1))) unsigned int* gas_ptr;
typedef __attribute__((address_space(3))) unsigned int* las_ptr;

__device__ __forceinline__ void async_copy16(const void* g, void* l) {
    // 16 B per lane; HW dest = wave-uniform base + lane*16
    __builtin_amdgcn_global_load_lds((gas_ptr)g, (las_ptr)l, 16, 0, 0);
}

union SharedU {
    float S[64][65];          // phase 1 transpose staging (16.6 KB)
    _Float16 G[2][6144];      // phase 2: per buf: A[0..2048) B[2048..6144) (24 KB)
    float red[DEPTH][4];      // phase 3 reduction slots
};

__global__ __launch_bounds__(256, 4) void mono_kernel(
        const float* __restrict__ x, const float* __restrict__ W,
        const float* __restrict__ b_enc, const float* __restrict__ ws,
        const float* __restrict__ bs, float* __restrict__ out,
        _Float16* __restrict__ xh, _Float16* __restrict__ Wt,
        float* __restrict__ h) {
    __shared__ SharedU u;
    const int b = blockIdx.x;
    const int t = threadIdx.x;
    cg::grid_group grid = cg::this_grid();

    // ================= phase 1: prep =================
    if (b < 256) {
        // transpose-cast W (fp32 [k][n]) -> Wt (f16 [n][k]), 64x64 tile
        const int k0 = (b >> 4) << 6;
        const int n0 = (b & 15) << 6;
#pragma unroll
        for (int i = 0; i < 4; ++i) {
            int idx = (i << 8) + t;
            int r = idx >> 4;              // k-local
            int c4 = idx & 15;             // float4 group along n
            float4 v = *(const float4*)(W + (size_t)(k0 + r) * H_SZ + n0 + (c4 << 2));
            u.S[r][(c4 << 2) + 0] = v.x;
            u.S[r][(c4 << 2) + 1] = v.y;
            u.S[r][(c4 << 2) + 2] = v.z;
            u.S[r][(c4 << 2) + 3] = v.w;
        }
        __syncthreads();
#pragma unroll
        for (int i = 0; i < 4; ++i) {
            int idx = (i << 8) + t;
            int n = idx >> 4;
            int c4 = idx & 15;
            int k = c4 << 2;
            half4_t o;
            o.x = (_Float16)u.S[k + 0][n];
            o.y = (_Float16)u.S[k + 1][n];
            o.z = (_Float16)u.S[k + 2][n];
            o.w = (_Float16)u.S[k + 3][n];
            *(half4_t*)(Wt + (size_t)(n0 + n) * D_SZ + k0 + k) = o;
        }
    } else {
        // cast x fp32 -> f16
        const int base = (b - 256) * 4096;
#pragma unroll
        for (int i = 0; i < 4; ++i) {
            int off = base + (((i << 8) + t) << 2);
            float4 v = *(const float4*)(x + off);
            half4_t o;
            o.x = (_Float16)v.x; o.y = (_Float16)v.y;
            o.z = (_Float16)v.z; o.w = (_Float16)v.w;
            *(half4_t*)(xh + off) = o;
        }
    }
    __threadfence();
    grid.sync();

    // ================= phase 2: GEMM =================
    {
        const int lane = t & 63;
        const int w    = t >> 6;           // 0..3
        const int m0 = (b >> 4) << 5;      // 32 m-tiles
        const int n0 = (b & 15) << 6;      // 16 n-tiles
        const int wm = (w >> 1) << 4;      // 0/16
        const int wn = (w & 1) << 5;       // 0/32

        // staging: slot s -> row s>>3, phys chunk s&7, logical = phys^(row&7)
        const int sr = t >> 3;             // 0..31
        const int sc = ((t & 7) ^ (sr & 7)) << 3;
        const _Float16* aSrc  = xh + (size_t)(m0 + sr) * D_SZ + sc;
        const _Float16* bSrc0 = Wt + (size_t)(n0 + sr) * D_SZ + sc;       // rows 0..31
        const _Float16* bSrc1 = Wt + (size_t)(n0 + sr + 32) * D_SZ + sc;  // rows 32..63

        // fragments (16x16x32): A[m=lane&15][k=q*8+j], B symmetric
        const int cq = lane & 15;
        const int q  = lane >> 4;
        const int ra  = wm + cq;           // A row 0..31
        const int rb0 = wn + cq;           // B rows for the 2 n-subtiles
        const int rb1 = wn + 16 + cq;

        floatx4_t acc0 = {0.f, 0.f, 0.f, 0.f};
        floatx4_t acc1 = {0.f, 0.f, 0.f, 0.f};

        // prologue: stage buffer 0
        async_copy16(aSrc,  &u.G[0][(w << 9)]);
        async_copy16(bSrc0, &u.G[0][2048 + (w << 9)]);
        async_copy16(bSrc1, &u.G[0][4096 + (w << 9)]);

        for (int it = 0; it < 16; ++it) {
            __syncthreads();               // buf[it&1] ready; buf[(it+1)&1] free
            if (it + 1 < 16) {
                const int k0 = (it + 1) << 6;
                _Float16* Gb = u.G[(it + 1) & 1];
                async_copy16(aSrc + k0,  Gb + (w << 9));
                async_copy16(bSrc0 + k0, Gb + 2048 + (w << 9));
                async_copy16(bSrc1 + k0, Gb + 4096 + (w << 9));
            }
            const _Float16* Gb = u.G[it & 1];
#pragma unroll
            for (int kc = 0; kc < 2; ++kc) {
                const int lc = (kc << 2) + q;
                half8_t af  = *(const half8_t*)(Gb + ra * 64 + ((lc ^ (ra & 7)) << 3));
                half8_t bf0 = *(const half8_t*)(Gb + 2048 + rb0 * 64 + ((lc ^ (rb0 & 7)) << 3));
                half8_t bf1 = *(const half8_t*)(Gb + 2048 + rb1 * 64 + ((lc ^ (rb1 & 7)) << 3));
                acc0 = __builtin_amdgcn_mfma_f32_16x16x32_f16(af, bf0, acc0, 0, 0, 0);
                acc1 = __builtin_amdgcn_mfma_f32_16x16x32_f16(af, bf1, acc1, 0, 0, 0);
            }
        }

        // C/D: col = lane&15, row = q*4 + reg
        const int col0 = n0 + wn + cq;
        const int col1 = col0 + 16;
        const int row0 = m0 + wm + (q << 2);
#pragma unroll
        for (int r = 0; r < 4; ++r) {
            h[(size_t)(row0 + r) * H_SZ + col0] = acc0[r];
            h[(size_t)(row0 + r) * H_SZ + col1] = acc1[r];
        }
    }
    __threadfence();
    grid.sync();

    // ================= phase 3: crossnet, 2 rows/block =================
    {
        float4 be = *(const float4*)(b_enc + (t << 2));
        float4 wv[DEPTH], bv[DEPTH];
#pragma unroll
        for (int l = 0; l < DEPTH; ++l) {
            wv[l] = *(const float4*)(ws + l * H_SZ + (t << 2));
            bv[l] = *(const float4*)(bs + l * H_SZ + (t << 2));
        }
        for (int rr = 0; rr < 2; ++rr) {
            const int row = (b << 1) + rr;
            const float* hr = h + (size_t)row * H_SZ;
            float4 hv = *(const float4*)(hr + (t << 2));
            float x0[4] = {hv.x + be.x, hv.y + be.y, hv.z + be.z, hv.w + be.w};
            float xl[4] = {x0[0], x0[1], x0[2], x0[3]};
#pragma unroll
            for (int l = 0; l < DEPTH; ++l) {
                float p = xl[0] * wv[l].x + xl[1] * wv[l].y
                        + xl[2] * wv[l].z + xl[3] * wv[l].w;
#pragma unroll
                for (int off = 32; off > 0; off >>= 1) p += __shfl_down(p, off, 64);
                if ((t & 63) == 0) u.red[l][t >> 6] = p;
                __syncthreads();           // per-layer slots -> no WAR hazard
                float s = u.red[l][0] + u.red[l][1] + u.red[l][2] + u.red[l][3];
                xl[0] += x0[0] * s + bv[l].x;
                xl[1] += x0[1] * s + bv[l].y;
                xl[2] += x0[2] * s + bv[l].z;
                xl[3] += x0[3] * s + bv[l].w;
            }
            float4 o = {xl[0], xl[1], xl[2], xl[3]};
            *(float4*)(out + (size_t)row * H_SZ + (t << 2)) = o;
        }
    }
}

extern "C" void kernel_launch(void* const* d_in, const int* in_sizes, int n_in,
                              void* d_out, int out_size, void* d_ws, size_t ws_size,
                              hipStream_t stream) {
    const float* x     = (const float*)d_in[0];
    const float* W_enc = (const float*)d_in[1];
    const float* b_enc = (const float*)d_in[2];
    const float* ws    = (const float*)d_in[3];
    const float* bs    = (const float*)d_in[4];
    float* out = (float*)d_out;

    _Float16* xh = (_Float16*)d_ws;                       // 2 MB
    _Float16* Wt = xh + (1 << 20);                        // 2 MB
    float*    h  = (float*)((char*)d_ws + (4u << 20));    // 4 MB

    void* args[] = {&x, &W_enc, &b_enc, &ws, &bs, &out, &xh, &Wt, &h};
    hipLaunchCooperativeKernel((const void*)mono_kernel, dim3(512), dim3(256),
                               args, 0, stream);
}

// Round 5
// 102.016 us; speedup vs baseline: 3.0778x; 3.0778x over previous
//
#include <hip/hip_runtime.h>
#include <hip/hip_bf16.h>

// CrossNetLayer: h = x @ W_enc + b_enc; then 4 cross layers
//   s = x_l . w_l (per row); x_l += x0 * s + b_l
// B = D = H = 1024, DEPTH = 4. fp32 in/out; GEMM internally f16 MFMA.
//
// R5: ALGEBRAIC COLLAPSE. x_l = a_l*x0 + sum_{j<l} b_j with a scalar-only
// per-row recurrence: a_{l+1} = a_l + a_l*d_l + g_l, d_l = x_row.v_l + e_l,
// v_l = W @ w_l (precomputed). So crossnet = GEMM epilogue:
//   out = a4*(acc + b_enc) + Bsum.   TWO dispatches, no grid.sync (R4's
// grid.sync cost ~100us each — abandoned), no h round-trip, no atomics.

#define DEPTH 4

typedef _Float16 half4_t __attribute__((ext_vector_type(4)));
typedef _Float16 half8_t __attribute__((ext_vector_type(8)));
typedef float floatx4_t __attribute__((ext_vector_type(4)));

typedef const __attribute__((address_space(1))) unsigned int* gas_ptr;
typedef __attribute__((address_space(3))) unsigned int* las_ptr;

__device__ __forceinline__ void async_copy16(const void* g, void* l) {
    // 16 B per lane; HW dest = wave-uniform base + lane*16
    __builtin_amdgcn_global_load_lds((gas_ptr)g, (las_ptr)l, 16, 0, 0);
}

__device__ __forceinline__ half4_t cvt4(float4 f) {
    half4_t o;
    o.x = (_Float16)f.x; o.y = (_Float16)f.y;
    o.z = (_Float16)f.z; o.w = (_Float16)f.w;
    return o;
}
__device__ __forceinline__ float dot4(float4 a, float4 b) {
    return a.x * b.x + a.y * b.y + a.z * b.z + a.w * b.w;
}

// ---------------------------------------------------------------------------
// Kernel 1: prep, 320 blocks x 256 thr.
//  b in [0,64):   W-block: rows k0..k0+15 full-n. Register volley (16 float4)
//                 -> v_l partials (shfl-reduce, direct store, NO atomics)
//                 -> 16 LDS-staged transpose tiles -> Wt f16 [n][k].
//  b in [64,320): x-cast block (f32 -> f16). Block 319 also e/g/Bsum.
// ---------------------------------------------------------------------------
__global__ __launch_bounds__(256) void prep_kernel(
        const float* __restrict__ x, const float* __restrict__ W,
        const float* __restrict__ b_enc, const float* __restrict__ ws,
        const float* __restrict__ bs, _Float16* __restrict__ xh,
        _Float16* __restrict__ Wt, float* __restrict__ v,
        float* __restrict__ eg, float* __restrict__ Bsum) {
    const int b = blockIdx.x;
    const int t = threadIdx.x;
    if (b < 64) {
        __shared__ _Float16 S16[16][66];   // pad 66: stage r/w ~2-way (free)
        const int k0 = b << 4;
        const int r  = t >> 4;             // k-local 0..15
        const int c4 = t & 15;             // 16-B column group
        const float* Wr = W + (size_t)(k0 + r) * 1024 + (c4 << 2);
        float4 w16[16];                    // full row volley: 1 latency hit
#pragma unroll
        for (int i = 0; i < 16; ++i) w16[i] = *(const float4*)(Wr + (i << 6));
        // v_l partials over this thread's n-slots
        float vp[4] = {0.f, 0.f, 0.f, 0.f};
#pragma unroll
        for (int i = 0; i < 16; ++i) {
#pragma unroll
            for (int l = 0; l < 4; ++l) {
                float4 wl = *(const float4*)(ws + l * 1024 + (c4 << 2) + (i << 6));
                vp[l] += dot4(w16[i], wl);
            }
        }
#pragma unroll
        for (int l = 0; l < 4; ++l) {
#pragma unroll
            for (int off = 8; off > 0; off >>= 1)
                vp[l] += __shfl_down(vp[l], off, 16);
        }
        if (c4 == 0) {
#pragma unroll
            for (int l = 0; l < 4; ++l) v[l * 1024 + k0 + r] = vp[l];
        }
        // transpose-cast: 16 tiles of 16k x 64n from registers via LDS
        for (int i = 0; i < 16; ++i) {
            __syncthreads();
            *(half4_t*)(&S16[r][c4 << 2]) = cvt4(w16[i]);
            __syncthreads();
            const int n   = t >> 2;        // 0..63
            const int sub = t & 3;         // k-subchunk (4 halfs)
            half4_t q;
            q.x = S16[(sub << 2) + 0][n];
            q.y = S16[(sub << 2) + 1][n];
            q.z = S16[(sub << 2) + 2][n];
            q.w = S16[(sub << 2) + 3][n];
            *(half4_t*)(Wt + (size_t)((i << 6) + n) * 1024 + k0 + (sub << 2)) = q;
        }
    } else {
        const int base = (b - 64) << 12;
#pragma unroll
        for (int i = 0; i < 4; ++i) {
            int off = base + (((i << 8) + t) << 2);
            *(half4_t*)(xh + off) = cvt4(*(const float4*)(x + off));
        }
        if (b == 319) {
            // e_l = b_enc.w_l ; g_l = (sum_{j<l} b_j).w_l ; Bsum = sum_l b_l
            __shared__ float egred[4][7];
            const int c = t << 2;
            float4 w0 = *(const float4*)(ws + c);
            float4 w1 = *(const float4*)(ws + 1024 + c);
            float4 w2 = *(const float4*)(ws + 2048 + c);
            float4 w3 = *(const float4*)(ws + 3072 + c);
            float4 q0 = *(const float4*)(bs + c);
            float4 q1 = *(const float4*)(bs + 1024 + c);
            float4 q2 = *(const float4*)(bs + 2048 + c);
            float4 q3 = *(const float4*)(bs + 3072 + c);
            float4 ben = *(const float4*)(b_enc + c);
            float4 B2, B3, Bs;
            B2.x = q0.x + q1.x; B2.y = q0.y + q1.y; B2.z = q0.z + q1.z; B2.w = q0.w + q1.w;
            B3.x = B2.x + q2.x; B3.y = B2.y + q2.y; B3.z = B2.z + q2.z; B3.w = B2.w + q2.w;
            Bs.x = B3.x + q3.x; Bs.y = B3.y + q3.y; Bs.z = B3.z + q3.z; Bs.w = B3.w + q3.w;
            *(float4*)(Bsum + c) = Bs;
            float vals[7];
            vals[0] = dot4(ben, w0); vals[1] = dot4(ben, w1);
            vals[2] = dot4(ben, w2); vals[3] = dot4(ben, w3);
            vals[4] = dot4(q0, w1);  vals[5] = dot4(B2, w2); vals[6] = dot4(B3, w3);
#pragma unroll
            for (int i = 0; i < 7; ++i)
#pragma unroll
                for (int off = 32; off > 0; off >>= 1)
                    vals[i] += __shfl_down(vals[i], off, 64);
            if ((t & 63) == 0)
#pragma unroll
                for (int i = 0; i < 7; ++i) egred[t >> 6][i] = vals[i];
            __syncthreads();
            if (t == 0) {
#pragma unroll
                for (int i = 0; i < 4; ++i)   // e0..e3
                    eg[i] = egred[0][i] + egred[1][i] + egred[2][i] + egred[3][i];
                eg[4] = 0.f;                   // g0
#pragma unroll
                for (int i = 4; i < 7; ++i)   // g1..g3
                    eg[i + 1] = egred[0][i] + egred[1][i] + egred[2][i] + egred[3][i];
            }
        }
    }
}

// ---------------------------------------------------------------------------
// Kernel 2: GEMM + crossnet epilogue. 512 blocks x 256 thr (4 waves).
// BM=32 BN=64 BK=64, dbuf XOR-swizzled LDS, global_load_lds (R4 phase-2
// core, validated). Pre-pass: d_l = xh_row.v_l (register-tiled, wave-local
// reduce) overlapped with buffer-0 staging; t<32 scalar recurrence -> a4.
// Epilogue: out = a4*(acc + b_enc) + Bsum.
// ---------------------------------------------------------------------------
__global__ __launch_bounds__(256) void gemm_kernel(
        const _Float16* __restrict__ xh, const _Float16* __restrict__ Wt,
        const float* __restrict__ b_enc, const float* __restrict__ v,
        const float* __restrict__ eg, const float* __restrict__ Bsum,
        float* __restrict__ out) {
    __shared__ _Float16 G[2][6144];     // per buf: A[0,2048) B[2048,6144)
    __shared__ float4 dred[32];
    __shared__ float a4s[32];
    const int t    = threadIdx.x;
    const int lane = t & 63;
    const int w    = t >> 6;
    const int m0 = (blockIdx.x >> 4) << 5;
    const int n0 = (blockIdx.x & 15) << 6;
    const int wm = (w >> 1) << 4;
    const int wn = (w & 1) << 5;

    // staging slots: row sr, phys chunk t&7 holds logical chunk (t&7)^(sr&7)
    const int sr = t >> 3;
    const int sc = ((t & 7) ^ (sr & 7)) << 3;
    const _Float16* aSrc  = xh + (size_t)(m0 + sr) * 1024 + sc;
    const _Float16* bSrc0 = Wt + (size_t)(n0 + sr) * 1024 + sc;
    const _Float16* bSrc1 = Wt + (size_t)(n0 + sr + 32) * 1024 + sc;

    // prologue: stage buffer 0 (flies during the d pre-pass)
    async_copy16(aSrc,  &G[0][(w << 9)]);
    async_copy16(bSrc0, &G[0][2048 + (w << 9)]);
    async_copy16(bSrc1, &G[0][4096 + (w << 9)]);

    // ---- d pre-pass: wave w owns local rows w*8..w*8+8; lane = k-chunk ----
    {
        const int kc = lane;               // 64 chunks of 16 k
        float d[8][4];
#pragma unroll
        for (int j = 0; j < 8; ++j)
#pragma unroll
            for (int l = 0; l < 4; ++l) d[j][l] = 0.f;
#pragma unroll
        for (int i = 0; i < 2; ++i) {
            const int k = (kc << 4) + (i << 3);
            float4 vv[4][2];
#pragma unroll
            for (int l = 0; l < 4; ++l) {
                vv[l][0] = *(const float4*)(v + l * 1024 + k);
                vv[l][1] = *(const float4*)(v + l * 1024 + k + 4);
            }
#pragma unroll
            for (int j = 0; j < 8; ++j) {
                half8_t a = *(const half8_t*)(xh + (size_t)(m0 + (w << 3) + j) * 1024 + k);
                float af[8];
#pragma unroll
                for (int e2 = 0; e2 < 8; ++e2) af[e2] = (float)a[e2];
#pragma unroll
                for (int l = 0; l < 4; ++l)
                    d[j][l] += af[0] * vv[l][0].x + af[1] * vv[l][0].y
                             + af[2] * vv[l][0].z + af[3] * vv[l][0].w
                             + af[4] * vv[l][1].x + af[5] * vv[l][1].y
                             + af[6] * vv[l][1].z + af[7] * vv[l][1].w;
            }
        }
#pragma unroll
        for (int j = 0; j < 8; ++j)
#pragma unroll
            for (int l = 0; l < 4; ++l)
#pragma unroll
                for (int off = 32; off > 0; off >>= 1)
                    d[j][l] += __shfl_down(d[j][l], off, 64);
        if (lane == 0)
#pragma unroll
            for (int j = 0; j < 8; ++j) {
                float4 dd = {d[j][0], d[j][1], d[j][2], d[j][3]};
                dred[(w << 3) + j] = dd;
            }
    }
    __syncthreads();   // dred ready; also drains buffer-0 async copies
    if (t < 32) {
        float4 D = dred[t];
        float4 e = *(const float4*)(eg);
        float4 g = *(const float4*)(eg + 4);
        float d0 = D.x + e.x, d1 = D.y + e.y, d2 = D.z + e.z, d3 = D.w + e.w;
        float a = 1.f;
        a += a * d0 + g.x;
        a += a * d1 + g.y;
        a += a * d2 + g.z;
        a += a * d3 + g.w;
        a4s[t] = a;
    }

    // ---- K-loop (R4 phase-2 core) ----
    const int cq = lane & 15;
    const int q  = lane >> 4;
    const int ra  = wm + cq;
    const int rb0 = wn + cq;
    const int rb1 = wn + 16 + cq;
    floatx4_t acc0 = {0.f, 0.f, 0.f, 0.f};
    floatx4_t acc1 = {0.f, 0.f, 0.f, 0.f};

    for (int it = 0; it < 16; ++it) {
        __syncthreads();
        if (it + 1 < 16) {
            const int kk = (it + 1) << 6;
            _Float16* Gb = G[(it + 1) & 1];
            async_copy16(aSrc + kk,  Gb + (w << 9));
            async_copy16(bSrc0 + kk, Gb + 2048 + (w << 9));
            async_copy16(bSrc1 + kk, Gb + 4096 + (w << 9));
        }
        const _Float16* Gb = G[it & 1];
#pragma unroll
        for (int kc2 = 0; kc2 < 2; ++kc2) {
            const int lc = (kc2 << 2) + q;
            half8_t af  = *(const half8_t*)(Gb + ra * 64 + ((lc ^ (ra & 7)) << 3));
            half8_t bf0 = *(const half8_t*)(Gb + 2048 + rb0 * 64 + ((lc ^ (rb0 & 7)) << 3));
            half8_t bf1 = *(const half8_t*)(Gb + 2048 + rb1 * 64 + ((lc ^ (rb1 & 7)) << 3));
            acc0 = __builtin_amdgcn_mfma_f32_16x16x32_f16(af, bf0, acc0, 0, 0, 0);
            acc1 = __builtin_amdgcn_mfma_f32_16x16x32_f16(af, bf1, acc1, 0, 0, 0);
        }
    }

    // ---- epilogue: out = a4*(acc + b_enc) + Bsum ----
    const int col0 = n0 + wn + cq;
    const int col1 = col0 + 16;
    const int row0 = m0 + wm + (q << 2);
    float4 a4f = *(const float4*)(&a4s[wm + (q << 2)]);
    float a4a[4] = {a4f.x, a4f.y, a4f.z, a4f.w};
    float be0 = b_enc[col0], be1 = b_enc[col1];
    float Bs0 = Bsum[col0],  Bs1 = Bsum[col1];
#pragma unroll
    for (int r = 0; r < 4; ++r) {
        out[(size_t)(row0 + r) * 1024 + col0] = a4a[r] * (acc0[r] + be0) + Bs0;
        out[(size_t)(row0 + r) * 1024 + col1] = a4a[r] * (acc1[r] + be1) + Bs1;
    }
}

extern "C" void kernel_launch(void* const* d_in, const int* in_sizes, int n_in,
                              void* d_out, int out_size, void* d_ws, size_t ws_size,
                              hipStream_t stream) {
    const float* x     = (const float*)d_in[0];
    const float* W_enc = (const float*)d_in[1];
    const float* b_enc = (const float*)d_in[2];
    const float* ws    = (const float*)d_in[3];
    const float* bs    = (const float*)d_in[4];
    float* out = (float*)d_out;

    _Float16* xh = (_Float16*)d_ws;                          // 2 MB
    _Float16* Wt = xh + (1 << 20);                           // 2 MB
    float*    v    = (float*)((char*)d_ws + (4u << 20));     // 16 KB
    float*    eg   = v + 4096;                               // 32 B
    float*    Bsum = eg + 8;                                 // 4 KB (16B-aligned)

    prep_kernel<<<320, 256, 0, stream>>>(x, W_enc, b_enc, ws, bs,
                                         xh, Wt, v, eg, Bsum);
    gemm_kernel<<<512, 256, 0, stream>>>(xh, Wt, b_enc, v, eg, Bsum, out);
}

// Round 6
// 89.408 us; speedup vs baseline: 3.5119x; 1.1410x over previous
//
#include <hip/hip_runtime.h>
#include <hip/hip_bf16.h>

// CrossNetLayer: h = x @ W_enc + b_enc; then 4 cross layers
//   s = x_l . w_l (per row); x_l += x0 * s + b_l
// B = D = H = 1024, DEPTH = 4. fp32 in/out; GEMM internally f16 MFMA.
//
// R6: R5's validated algebra (crossnet == scalar recurrence ->
// out = a4*(h+b_enc)+Bsum, v_l = W@w_l precomputed) with the prep
// rebuilt: R5's prep dynamically indexed a 16xfloat4 register array
// (no unroll) -> scratch spill in a 32-barrier loop = ~+20us. Now:
// R2's proven 64x64 LDS transpose (256 blk) + x-cast (256 blk) +
// barrier-free v-rows (128 blk) + eg/Bsum (1 blk). Gemm unchanged.

#define DEPTH 4

typedef _Float16 half4_t __attribute__((ext_vector_type(4)));
typedef _Float16 half8_t __attribute__((ext_vector_type(8)));
typedef float floatx4_t __attribute__((ext_vector_type(4)));

typedef const __attribute__((address_space(1))) unsigned int* gas_ptr;
typedef __attribute__((address_space(3))) unsigned int* las_ptr;

__device__ __forceinline__ void async_copy16(const void* g, void* l) {
    // 16 B per lane; HW dest = wave-uniform base + lane*16
    __builtin_amdgcn_global_load_lds((gas_ptr)g, (las_ptr)l, 16, 0, 0);
}

__device__ __forceinline__ half4_t cvt4(float4 f) {
    half4_t o;
    o.x = (_Float16)f.x; o.y = (_Float16)f.y;
    o.z = (_Float16)f.z; o.w = (_Float16)f.w;
    return o;
}
__device__ __forceinline__ float dot4(float4 a, float4 b) {
    return a.x * b.x + a.y * b.y + a.z * b.z + a.w * b.w;
}

// ---------------------------------------------------------------------------
// Kernel 1: prep, 641 blocks x 256 thr.
//  b in [0,256):   transpose-cast W (fp32 [k][n]) -> Wt (f16 [n][k]), 64x64
//  b in [256,512): cast x fp32 -> f16
//  b in [512,640): v_l[k] = W[k,:].w_l  (8 rows/block, 32 lanes/row)
//  b == 640:       e_l, g_l, Bsum scalars
// ---------------------------------------------------------------------------
__global__ __launch_bounds__(256) void prep_kernel(
        const float* __restrict__ x, const float* __restrict__ W,
        const float* __restrict__ b_enc, const float* __restrict__ ws,
        const float* __restrict__ bs, _Float16* __restrict__ xh,
        _Float16* __restrict__ Wt, float* __restrict__ v,
        float* __restrict__ eg, float* __restrict__ Bsum) {
    const int b = blockIdx.x;
    const int t = threadIdx.x;
    if (b < 256) {
        __shared__ float S[64][65];    // +1 pad: transposed reads conflict-free
        const int k0 = (b >> 4) << 6;
        const int n0 = (b & 15) << 6;
#pragma unroll
        for (int i = 0; i < 4; ++i) {
            int idx = (i << 8) + t;
            int r = idx >> 4;              // k-local 0..63
            int c4 = idx & 15;             // float4 group along n
            float4 vv = *(const float4*)(W + (size_t)(k0 + r) * 1024 + n0 + (c4 << 2));
            S[r][(c4 << 2) + 0] = vv.x;
            S[r][(c4 << 2) + 1] = vv.y;
            S[r][(c4 << 2) + 2] = vv.z;
            S[r][(c4 << 2) + 3] = vv.w;
        }
        __syncthreads();
#pragma unroll
        for (int i = 0; i < 4; ++i) {
            int idx = (i << 8) + t;
            int n = idx >> 4;              // n-local 0..63
            int c4 = idx & 15;
            int k = c4 << 2;
            half4_t o;
            o.x = (_Float16)S[k + 0][n];
            o.y = (_Float16)S[k + 1][n];
            o.z = (_Float16)S[k + 2][n];
            o.w = (_Float16)S[k + 3][n];
            *(half4_t*)(Wt + (size_t)(n0 + n) * 1024 + k0 + k) = o;
        }
    } else if (b < 512) {
        const int base = (b - 256) << 12;
#pragma unroll
        for (int i = 0; i < 4; ++i) {
            int off = base + (((i << 8) + t) << 2);
            *(half4_t*)(xh + off) = cvt4(*(const float4*)(x + off));
        }
    } else if (b < 640) {
        // v rows: row = (b-512)*8 + t/32 ; 32 lanes sweep the 1024 cols
        const int row = ((b - 512) << 3) + (t >> 5);
        const int l32 = t & 31;
        const float* Wr = W + (size_t)row * 1024 + (l32 << 2);
        float vp[4] = {0.f, 0.f, 0.f, 0.f};
#pragma unroll
        for (int i = 0; i < 8; ++i) {
            float4 wr = *(const float4*)(Wr + (i << 7));
#pragma unroll
            for (int l = 0; l < 4; ++l) {
                float4 wl = *(const float4*)(ws + l * 1024 + (l32 << 2) + (i << 7));
                vp[l] += dot4(wr, wl);
            }
        }
#pragma unroll
        for (int l = 0; l < 4; ++l)
#pragma unroll
            for (int off = 16; off > 0; off >>= 1)
                vp[l] += __shfl_down(vp[l], off, 32);
        if (l32 == 0) {
#pragma unroll
            for (int l = 0; l < 4; ++l) v[l * 1024 + row] = vp[l];
        }
    } else {
        // e_l = b_enc.w_l ; g_l = (sum_{j<l} b_j).w_l ; Bsum = sum_l b_l
        __shared__ float egred[4][7];
        const int c = t << 2;
        float4 w0 = *(const float4*)(ws + c);
        float4 w1 = *(const float4*)(ws + 1024 + c);
        float4 w2 = *(const float4*)(ws + 2048 + c);
        float4 w3 = *(const float4*)(ws + 3072 + c);
        float4 q0 = *(const float4*)(bs + c);
        float4 q1 = *(const float4*)(bs + 1024 + c);
        float4 q2 = *(const float4*)(bs + 2048 + c);
        float4 q3 = *(const float4*)(bs + 3072 + c);
        float4 ben = *(const float4*)(b_enc + c);
        float4 B2, B3, Bs;
        B2.x = q0.x + q1.x; B2.y = q0.y + q1.y; B2.z = q0.z + q1.z; B2.w = q0.w + q1.w;
        B3.x = B2.x + q2.x; B3.y = B2.y + q2.y; B3.z = B2.z + q2.z; B3.w = B2.w + q2.w;
        Bs.x = B3.x + q3.x; Bs.y = B3.y + q3.y; Bs.z = B3.z + q3.z; Bs.w = B3.w + q3.w;
        *(float4*)(Bsum + c) = Bs;
        float vals[7];
        vals[0] = dot4(ben, w0); vals[1] = dot4(ben, w1);
        vals[2] = dot4(ben, w2); vals[3] = dot4(ben, w3);
        vals[4] = dot4(q0, w1);  vals[5] = dot4(B2, w2); vals[6] = dot4(B3, w3);
#pragma unroll
        for (int i = 0; i < 7; ++i)
#pragma unroll
            for (int off = 32; off > 0; off >>= 1)
                vals[i] += __shfl_down(vals[i], off, 64);
        if ((t & 63) == 0)
#pragma unroll
            for (int i = 0; i < 7; ++i) egred[t >> 6][i] = vals[i];
        __syncthreads();
        if (t == 0) {
#pragma unroll
            for (int i = 0; i < 4; ++i)       // e0..e3
                eg[i] = egred[0][i] + egred[1][i] + egred[2][i] + egred[3][i];
            eg[4] = 0.f;                       // g0
#pragma unroll
            for (int i = 4; i < 7; ++i)       // g1..g3
                eg[i + 1] = egred[0][i] + egred[1][i] + egred[2][i] + egred[3][i];
        }
    }
}

// ---------------------------------------------------------------------------
// Kernel 2 (unchanged from R5, validated): GEMM + crossnet epilogue.
// 512 blocks x 256 thr. BM=32 BN=64 BK=64, dbuf XOR-swizzled LDS,
// global_load_lds. d pre-pass overlapped with buffer-0 staging.
// Epilogue: out = a4*(acc + b_enc) + Bsum.
// ---------------------------------------------------------------------------
__global__ __launch_bounds__(256) void gemm_kernel(
        const _Float16* __restrict__ xh, const _Float16* __restrict__ Wt,
        const float* __restrict__ b_enc, const float* __restrict__ v,
        const float* __restrict__ eg, const float* __restrict__ Bsum,
        float* __restrict__ out) {
    __shared__ _Float16 G[2][6144];     // per buf: A[0,2048) B[2048,6144)
    __shared__ float4 dred[32];
    __shared__ float a4s[32];
    const int t    = threadIdx.x;
    const int lane = t & 63;
    const int w    = t >> 6;
    const int m0 = (blockIdx.x >> 4) << 5;
    const int n0 = (blockIdx.x & 15) << 6;
    const int wm = (w >> 1) << 4;
    const int wn = (w & 1) << 5;

    const int sr = t >> 3;
    const int sc = ((t & 7) ^ (sr & 7)) << 3;
    const _Float16* aSrc  = xh + (size_t)(m0 + sr) * 1024 + sc;
    const _Float16* bSrc0 = Wt + (size_t)(n0 + sr) * 1024 + sc;
    const _Float16* bSrc1 = Wt + (size_t)(n0 + sr + 32) * 1024 + sc;

    async_copy16(aSrc,  &G[0][(w << 9)]);
    async_copy16(bSrc0, &G[0][2048 + (w << 9)]);
    async_copy16(bSrc1, &G[0][4096 + (w << 9)]);

    // ---- d pre-pass: wave w owns local rows w*8..w*8+7; lane = k-chunk ----
    {
        const int kc = lane;
        float d[8][4];
#pragma unroll
        for (int j = 0; j < 8; ++j)
#pragma unroll
            for (int l = 0; l < 4; ++l) d[j][l] = 0.f;
#pragma unroll
        for (int i = 0; i < 2; ++i) {
            const int k = (kc << 4) + (i << 3);
            float4 vv[4][2];
#pragma unroll
            for (int l = 0; l < 4; ++l) {
                vv[l][0] = *(const float4*)(v + l * 1024 + k);
                vv[l][1] = *(const float4*)(v + l * 1024 + k + 4);
            }
#pragma unroll
            for (int j = 0; j < 8; ++j) {
                half8_t a = *(const half8_t*)(xh + (size_t)(m0 + (w << 3) + j) * 1024 + k);
                float af[8];
#pragma unroll
                for (int e2 = 0; e2 < 8; ++e2) af[e2] = (float)a[e2];
#pragma unroll
                for (int l = 0; l < 4; ++l)
                    d[j][l] += af[0] * vv[l][0].x + af[1] * vv[l][0].y
                             + af[2] * vv[l][0].z + af[3] * vv[l][0].w
                             + af[4] * vv[l][1].x + af[5] * vv[l][1].y
                             + af[6] * vv[l][1].z + af[7] * vv[l][1].w;
            }
        }
#pragma unroll
        for (int j = 0; j < 8; ++j)
#pragma unroll
            for (int l = 0; l < 4; ++l)
#pragma unroll
                for (int off = 32; off > 0; off >>= 1)
                    d[j][l] += __shfl_down(d[j][l], off, 64);
        if (lane == 0)
#pragma unroll
            for (int j = 0; j < 8; ++j) {
                float4 dd = {d[j][0], d[j][1], d[j][2], d[j][3]};
                dred[(w << 3) + j] = dd;
            }
    }
    __syncthreads();   // dred ready; also drains buffer-0 async copies
    if (t < 32) {
        float4 D = dred[t];
        float4 e = *(const float4*)(eg);
        float4 g = *(const float4*)(eg + 4);
        float d0 = D.x + e.x, d1 = D.y + e.y, d2 = D.z + e.z, d3 = D.w + e.w;
        float a = 1.f;
        a += a * d0 + g.x;
        a += a * d1 + g.y;
        a += a * d2 + g.z;
        a += a * d3 + g.w;
        a4s[t] = a;
    }

    // ---- K-loop ----
    const int cq = lane & 15;
    const int q  = lane >> 4;
    const int ra  = wm + cq;
    const int rb0 = wn + cq;
    const int rb1 = wn + 16 + cq;
    floatx4_t acc0 = {0.f, 0.f, 0.f, 0.f};
    floatx4_t acc1 = {0.f, 0.f, 0.f, 0.f};

    for (int it = 0; it < 16; ++it) {
        __syncthreads();
        if (it + 1 < 16) {
            const int kk = (it + 1) << 6;
            _Float16* Gb = G[(it + 1) & 1];
            async_copy16(aSrc + kk,  Gb + (w << 9));
            async_copy16(bSrc0 + kk, Gb + 2048 + (w << 9));
            async_copy16(bSrc1 + kk, Gb + 4096 + (w << 9));
        }
        const _Float16* Gb = G[it & 1];
#pragma unroll
        for (int kc2 = 0; kc2 < 2; ++kc2) {
            const int lc = (kc2 << 2) + q;
            half8_t af  = *(const half8_t*)(Gb + ra * 64 + ((lc ^ (ra & 7)) << 3));
            half8_t bf0 = *(const half8_t*)(Gb + 2048 + rb0 * 64 + ((lc ^ (rb0 & 7)) << 3));
            half8_t bf1 = *(const half8_t*)(Gb + 2048 + rb1 * 64 + ((lc ^ (rb1 & 7)) << 3));
            acc0 = __builtin_amdgcn_mfma_f32_16x16x32_f16(af, bf0, acc0, 0, 0, 0);
            acc1 = __builtin_amdgcn_mfma_f32_16x16x32_f16(af, bf1, acc1, 0, 0, 0);
        }
    }

    // ---- epilogue: out = a4*(acc + b_enc) + Bsum ----
    const int col0 = n0 + wn + cq;
    const int col1 = col0 + 16;
    const int row0 = m0 + wm + (q << 2);
    float4 a4f = *(const float4*)(&a4s[wm + (q << 2)]);
    float a4a[4] = {a4f.x, a4f.y, a4f.z, a4f.w};
    float be0 = b_enc[col0], be1 = b_enc[col1];
    float Bs0 = Bsum[col0],  Bs1 = Bsum[col1];
#pragma unroll
    for (int r = 0; r < 4; ++r) {
        out[(size_t)(row0 + r) * 1024 + col0] = a4a[r] * (acc0[r] + be0) + Bs0;
        out[(size_t)(row0 + r) * 1024 + col1] = a4a[r] * (acc1[r] + be1) + Bs1;
    }
}

extern "C" void kernel_launch(void* const* d_in, const int* in_sizes, int n_in,
                              void* d_out, int out_size, void* d_ws, size_t ws_size,
                              hipStream_t stream) {
    const float* x     = (const float*)d_in[0];
    const float* W_enc = (const float*)d_in[1];
    const float* b_enc = (const float*)d_in[2];
    const float* ws    = (const float*)d_in[3];
    const float* bs    = (const float*)d_in[4];
    float* out = (float*)d_out;

    _Float16* xh = (_Float16*)d_ws;                          // 2 MB
    _Float16* Wt = xh + (1 << 20);                           // 2 MB
    float*    v    = (float*)((char*)d_ws + (4u << 20));     // 16 KB
    float*    eg   = v + 4096;                               // 32 B
    float*    Bsum = eg + 8;                                 // 4 KB

    prep_kernel<<<641, 256, 0, stream>>>(x, W_enc, b_enc, ws, bs,
                                         xh, Wt, v, eg, Bsum);
    gemm_kernel<<<512, 256, 0, stream>>>(xh, Wt, b_enc, v, eg, Bsum, out);
}

// Round 7
// 84.507 us; speedup vs baseline: 3.7156x; 1.0580x over previous
//
#include <hip/hip_runtime.h>
#include <hip/hip_bf16.h>

// CrossNetLayer: h = x @ W_enc + b_enc; then 4 cross layers
//   s = x_l . w_l (per row); x_l += x0 * s + b_l
// B = D = H = 1024, DEPTH = 4. fp32 in/out; GEMM internally f16 MFMA.
//
// R7: R5/R6 algebra (out = a4*(h+b_enc)+Bsum, a4 from scalar recurrence on
// d_l = x_row.v_l + e_l, v_l = W@w_l). R6's d pre-pass did 192 shfl/wave
// (ds_bpermute -> DS pipe, ~8-10us). R7 computes d ON THE MFMA PIPE as a
// third accumulator in the main K-loop (B-operand = f16 vh rows staged in
// LDS once). Zero shuffles in the gemm.

#define DEPTH 4

typedef _Float16 half4_t __attribute__((ext_vector_type(4)));
typedef _Float16 half8_t __attribute__((ext_vector_type(8)));
typedef float floatx4_t __attribute__((ext_vector_type(4)));

typedef const __attribute__((address_space(1))) unsigned int* gas_ptr;
typedef __attribute__((address_space(3))) unsigned int* las_ptr;

__device__ __forceinline__ void async_copy16(const void* g, void* l) {
    // 16 B per lane; HW dest = wave-uniform base + lane*16
    __builtin_amdgcn_global_load_lds((gas_ptr)g, (las_ptr)l, 16, 0, 0);
}

__device__ __forceinline__ half4_t cvt4(float4 f) {
    half4_t o;
    o.x = (_Float16)f.x; o.y = (_Float16)f.y;
    o.z = (_Float16)f.z; o.w = (_Float16)f.w;
    return o;
}
__device__ __forceinline__ float dot4(float4 a, float4 b) {
    return a.x * b.x + a.y * b.y + a.z * b.z + a.w * b.w;
}

// ---------------------------------------------------------------------------
// Kernel 1: prep, 641 blocks x 256 thr.
//  b in [0,256):   transpose-cast W (fp32 [k][n]) -> Wt (f16 [n][k]), 64x64
//  b in [256,512): cast x fp32 -> f16
//  b in [512,640): vh[l][k] = W[k,:].w_l  (f16; 8 rows/block, 32 lanes/row)
//  b == 640:       e_l, g_l, Bsum scalars
// ---------------------------------------------------------------------------
__global__ __launch_bounds__(256) void prep_kernel(
        const float* __restrict__ x, const float* __restrict__ W,
        const float* __restrict__ b_enc, const float* __restrict__ ws,
        const float* __restrict__ bs, _Float16* __restrict__ xh,
        _Float16* __restrict__ Wt, _Float16* __restrict__ vh,
        float* __restrict__ eg, float* __restrict__ Bsum) {
    const int b = blockIdx.x;
    const int t = threadIdx.x;
    if (b < 256) {
        __shared__ float S[64][65];    // +1 pad: transposed reads conflict-free
        const int k0 = (b >> 4) << 6;
        const int n0 = (b & 15) << 6;
#pragma unroll
        for (int i = 0; i < 4; ++i) {
            int idx = (i << 8) + t;
            int r = idx >> 4;              // k-local 0..63
            int c4 = idx & 15;             // float4 group along n
            float4 vv = *(const float4*)(W + (size_t)(k0 + r) * 1024 + n0 + (c4 << 2));
            S[r][(c4 << 2) + 0] = vv.x;
            S[r][(c4 << 2) + 1] = vv.y;
            S[r][(c4 << 2) + 2] = vv.z;
            S[r][(c4 << 2) + 3] = vv.w;
        }
        __syncthreads();
#pragma unroll
        for (int i = 0; i < 4; ++i) {
            int idx = (i << 8) + t;
            int n = idx >> 4;              // n-local 0..63
            int c4 = idx & 15;
            int k = c4 << 2;
            half4_t o;
            o.x = (_Float16)S[k + 0][n];
            o.y = (_Float16)S[k + 1][n];
            o.z = (_Float16)S[k + 2][n];
            o.w = (_Float16)S[k + 3][n];
            *(half4_t*)(Wt + (size_t)(n0 + n) * 1024 + k0 + k) = o;
        }
    } else if (b < 512) {
        const int base = (b - 256) << 12;
#pragma unroll
        for (int i = 0; i < 4; ++i) {
            int off = base + (((i << 8) + t) << 2);
            *(half4_t*)(xh + off) = cvt4(*(const float4*)(x + off));
        }
    } else if (b < 640) {
        // vh rows: row = (b-512)*8 + t/32 ; 32 lanes sweep the 1024 cols
        const int row = ((b - 512) << 3) + (t >> 5);
        const int l32 = t & 31;
        const float* Wr = W + (size_t)row * 1024 + (l32 << 2);
        float vp[4] = {0.f, 0.f, 0.f, 0.f};
#pragma unroll
        for (int i = 0; i < 8; ++i) {
            float4 wr = *(const float4*)(Wr + (i << 7));
#pragma unroll
            for (int l = 0; l < 4; ++l) {
                float4 wl = *(const float4*)(ws + l * 1024 + (l32 << 2) + (i << 7));
                vp[l] += dot4(wr, wl);
            }
        }
#pragma unroll
        for (int l = 0; l < 4; ++l)
#pragma unroll
            for (int off = 16; off > 0; off >>= 1)
                vp[l] += __shfl_down(vp[l], off, 32);
        if (l32 == 0) {
#pragma unroll
            for (int l = 0; l < 4; ++l) vh[(l << 10) + row] = (_Float16)vp[l];
        }
    } else {
        // e_l = b_enc.w_l ; g_l = (sum_{j<l} b_j).w_l ; Bsum = sum_l b_l
        __shared__ float egred[4][7];
        const int c = t << 2;
        float4 w0 = *(const float4*)(ws + c);
        float4 w1 = *(const float4*)(ws + 1024 + c);
        float4 w2 = *(const float4*)(ws + 2048 + c);
        float4 w3 = *(const float4*)(ws + 3072 + c);
        float4 q0 = *(const float4*)(bs + c);
        float4 q1 = *(const float4*)(bs + 1024 + c);
        float4 q2 = *(const float4*)(bs + 2048 + c);
        float4 q3 = *(const float4*)(bs + 3072 + c);
        float4 ben = *(const float4*)(b_enc + c);
        float4 B2, B3, Bs;
        B2.x = q0.x + q1.x; B2.y = q0.y + q1.y; B2.z = q0.z + q1.z; B2.w = q0.w + q1.w;
        B3.x = B2.x + q2.x; B3.y = B2.y + q2.y; B3.z = B2.z + q2.z; B3.w = B2.w + q2.w;
        Bs.x = B3.x + q3.x; Bs.y = B3.y + q3.y; Bs.z = B3.z + q3.z; Bs.w = B3.w + q3.w;
        *(float4*)(Bsum + c) = Bs;
        float vals[7];
        vals[0] = dot4(ben, w0); vals[1] = dot4(ben, w1);
        vals[2] = dot4(ben, w2); vals[3] = dot4(ben, w3);
        vals[4] = dot4(q0, w1);  vals[5] = dot4(B2, w2); vals[6] = dot4(B3, w3);
#pragma unroll
        for (int i = 0; i < 7; ++i)
#pragma unroll
            for (int off = 32; off > 0; off >>= 1)
                vals[i] += __shfl_down(vals[i], off, 64);
        if ((t & 63) == 0)
#pragma unroll
            for (int i = 0; i < 7; ++i) egred[t >> 6][i] = vals[i];
        __syncthreads();
        if (t == 0) {
#pragma unroll
            for (int i = 0; i < 4; ++i)       // e0..e3
                eg[i] = egred[0][i] + egred[1][i] + egred[2][i] + egred[3][i];
            eg[4] = 0.f;                       // g0
#pragma unroll
            for (int i = 4; i < 7; ++i)       // g1..g3
                eg[i + 1] = egred[0][i] + egred[1][i] + egred[2][i] + egred[3][i];
        }
    }
}

// ---------------------------------------------------------------------------
// Kernel 2: GEMM + crossnet epilogue. 512 blocks x 256 thr. BM=32 BN=64
// BK=64, dbuf XOR-swizzled LDS, global_load_lds. Third MFMA accumulator
// computes d[row][l] = xh_row . v_l in the same K-loop (B-operand = vhs).
// Epilogue: scalar recurrence -> a4; out = a4*(acc + b_enc) + Bsum.
// ---------------------------------------------------------------------------
__global__ __launch_bounds__(256) void gemm_kernel(
        const _Float16* __restrict__ xh, const _Float16* __restrict__ Wt,
        const float* __restrict__ b_enc, const _Float16* __restrict__ vh,
        const float* __restrict__ eg, const float* __restrict__ Bsum,
        float* __restrict__ out) {
    __shared__ _Float16 G[2][6144];     // per buf: A[0,2048) B[2048,6144)
    __shared__ _Float16 vhs[4][1032];   // +8 pad: frag reads <=2-way (free)
    __shared__ float dS[32][4];         // d[row][l] exchange
    const int t    = threadIdx.x;
    const int lane = t & 63;
    const int w    = t >> 6;
    const int m0 = (blockIdx.x >> 4) << 5;
    const int n0 = (blockIdx.x & 15) << 6;
    const int wm = (w >> 1) << 4;
    const int wn = (w & 1) << 5;

    const int sr = t >> 3;
    const int sc = ((t & 7) ^ (sr & 7)) << 3;
    const _Float16* aSrc  = xh + (size_t)(m0 + sr) * 1024 + sc;
    const _Float16* bSrc0 = Wt + (size_t)(n0 + sr) * 1024 + sc;
    const _Float16* bSrc1 = Wt + (size_t)(n0 + sr + 32) * 1024 + sc;

    // prologue: stage buffer 0 + vh rows 0..3 (first barrier covers both)
    async_copy16(aSrc,  &G[0][(w << 9)]);
    async_copy16(bSrc0, &G[0][2048 + (w << 9)]);
    async_copy16(bSrc1, &G[0][4096 + (w << 9)]);
    {
        const int r  = t >> 6;             // 0..3
        const int ln = t & 63;
        *(half8_t*)(&vhs[r][ln << 3]) =
            *(const half8_t*)(vh + (r << 10) + (ln << 3));
        *(half8_t*)(&vhs[r][(ln << 3) + 512]) =
            *(const half8_t*)(vh + (r << 10) + (ln << 3) + 512);
    }

    // fragments (16x16x32): A[m=lane&15][k=q*8+j], B symmetric
    const int cq = lane & 15;
    const int q  = lane >> 4;
    const int ra  = wm + cq;
    const int rb0 = wn + cq;
    const int rb1 = wn + 16 + cq;
    // v B-operand: column cq (= layer index) -> vhs row cq; lanes cq>=4 read
    // row cq&3 (in-bounds; contributes only to ignored D cols 4..15)
    const _Float16* vrow = &vhs[cq & 3][q << 3];

    floatx4_t acc0 = {0.f, 0.f, 0.f, 0.f};
    floatx4_t acc1 = {0.f, 0.f, 0.f, 0.f};
    floatx4_t dacc = {0.f, 0.f, 0.f, 0.f};

    for (int it = 0; it < 16; ++it) {
        __syncthreads();
        if (it + 1 < 16) {
            const int kk = (it + 1) << 6;
            _Float16* Gb = G[(it + 1) & 1];
            async_copy16(aSrc + kk,  Gb + (w << 9));
            async_copy16(bSrc0 + kk, Gb + 2048 + (w << 9));
            async_copy16(bSrc1 + kk, Gb + 4096 + (w << 9));
        }
        const _Float16* Gb = G[it & 1];
#pragma unroll
        for (int kc2 = 0; kc2 < 2; ++kc2) {
            const int lc = (kc2 << 2) + q;
            half8_t af  = *(const half8_t*)(Gb + ra * 64 + ((lc ^ (ra & 7)) << 3));
            half8_t bf0 = *(const half8_t*)(Gb + 2048 + rb0 * 64 + ((lc ^ (rb0 & 7)) << 3));
            half8_t bf1 = *(const half8_t*)(Gb + 2048 + rb1 * 64 + ((lc ^ (rb1 & 7)) << 3));
            half8_t vf  = *(const half8_t*)(vrow + (it << 6) + (kc2 << 5));
            acc0 = __builtin_amdgcn_mfma_f32_16x16x32_f16(af, bf0, acc0, 0, 0, 0);
            acc1 = __builtin_amdgcn_mfma_f32_16x16x32_f16(af, bf1, acc1, 0, 0, 0);
            dacc = __builtin_amdgcn_mfma_f32_16x16x32_f16(af, vf, dacc, 0, 0, 0);
        }
    }

    // ---- d exchange: D[m=q*4+r][n=cq], cols 0..3 = layers ----
    if (((w & 1) == 0) && cq < 4) {
#pragma unroll
        for (int r = 0; r < 4; ++r) dS[wm + (q << 2) + r][cq] = dacc[r];
    }
    __syncthreads();

    // ---- epilogue: a4 recurrence + out = a4*(acc + b_enc) + Bsum ----
    const float4 e  = *(const float4*)(eg);
    const float4 g4 = *(const float4*)(eg + 4);
    const int col0 = n0 + wn + cq;
    const int col1 = col0 + 16;
    const int row0 = m0 + wm + (q << 2);
    const float be0 = b_enc[col0], be1 = b_enc[col1];
    const float Bs0 = Bsum[col0],  Bs1 = Bsum[col1];
#pragma unroll
    for (int r = 0; r < 4; ++r) {
        float4 dv = *(const float4*)(&dS[wm + (q << 2) + r][0]);  // broadcast
        float a = 1.f;
        a += a * (dv.x + e.x) + g4.x;
        a += a * (dv.y + e.y) + g4.y;
        a += a * (dv.z + e.z) + g4.z;
        a += a * (dv.w + e.w) + g4.w;
        out[(size_t)(row0 + r) * 1024 + col0] = a * (acc0[r] + be0) + Bs0;
        out[(size_t)(row0 + r) * 1024 + col1] = a * (acc1[r] + be1) + Bs1;
    }
}

extern "C" void kernel_launch(void* const* d_in, const int* in_sizes, int n_in,
                              void* d_out, int out_size, void* d_ws, size_t ws_size,
                              hipStream_t stream) {
    const float* x     = (const float*)d_in[0];
    const float* W_enc = (const float*)d_in[1];
    const float* b_enc = (const float*)d_in[2];
    const float* ws    = (const float*)d_in[3];
    const float* bs    = (const float*)d_in[4];
    float* out = (float*)d_out;

    _Float16* xh = (_Float16*)d_ws;                          // 2 MB
    _Float16* Wt = xh + (1 << 20);                           // 2 MB
    _Float16* vh = Wt + (1 << 20);                           // 8 KB (f16 [4][1024])
    float*    eg   = (float*)((char*)d_ws + (4u << 20) + 8192);  // 32 B
    float*    Bsum = eg + 8;                                 // 4 KB

    prep_kernel<<<641, 256, 0, stream>>>(x, W_enc, b_enc, ws, bs,
                                         xh, Wt, vh, eg, Bsum);
    gemm_kernel<<<512, 256, 0, stream>>>(xh, Wt, b_enc, vh, eg, Bsum, out);
}